// Round 5
// baseline (1939.046 us; speedup 1.0000x reference)
//
#include <hip/hip_runtime.h>

// CapsNet dynamic routing, B=256 N=2048 C=10 D_IN=8 D_OUT=16, ROUTING_ITERS=3.
// R5 == R4 with ONE change: no per-thread arrays / address-taken values in
// caps_phase. R4's counters showed ~130 MB symmetric phantom TCC read+write
// (~150 floats/thread round-trip) + ~300cy/instr serialization = scratch
// demotion of the softmax array (address-taken c[10] under register pressure).
// Softmax now uses 10 named scalars via macro-unrolled per-j passes.
// Everything else identical: W staged in LDS (coalesced float4), slds atomic
// s-accumulator (R1-proven), half-wave i-split (2-addr LDS broadcasts = free),
// bg-in-high-bits XCD swizzle, LDS 60 KiB -> 2 blocks/CU.
// ws: s_part [128][160][256] f32 (20.97 MB) + vT0 + vsumT (160 KB each).

#define B_SZ  256
#define N_SZ  2048
#define C_SZ  10
#define DIN   8
#define DOUT  16
#define JO    (C_SZ*DOUT)     // 160
#define IC    16              // i's per chunk
#define NCH   (N_SZ/IC)       // 128 chunks
#define IPR   8               // i's staged per round (2 rounds)
#define WROW  (JO*DIN)        // 1280 floats per i
#define BSUB  32              // b's per block
#define NBG   (B_SZ/BSUB)     // 8 b-groups

// uh = dot(W_row[jo], u_row) -- all operands named float4 values / LDS reads
#define UH_JO(JO_, UH_) do {                                                   \
    const float* wrow_ = wbase + (JO_)*DIN;                                    \
    const float4 w0_ = ((const float4*)wrow_)[0];                              \
    const float4 w1_ = ((const float4*)wrow_)[1];                              \
    UH_ = w0_.x*ua.x;                                                          \
    UH_ = fmaf(w0_.y, ua.y, UH_); UH_ = fmaf(w0_.z, ua.z, UH_);                \
    UH_ = fmaf(w0_.w, ua.w, UH_);                                              \
    UH_ = fmaf(w1_.x, ub.x, UH_); UH_ = fmaf(w1_.y, ub.y, UH_);                \
    UH_ = fmaf(w1_.z, ub.z, UH_); UH_ = fmaf(w1_.w, ub.w, UH_);                \
} while (0)

#define PASS1_J(J_, A_) do {                                                   \
    float acc_ = 0.f;                                                          \
    _Pragma("unroll")                                                          \
    for (int o = 0; o < DOUT; ++o) {                                           \
        const int jo_ = (J_)*DOUT + o;                                         \
        float uh_; UH_JO(jo_, uh_);                                            \
        acc_ = fmaf(uh_, vT[jo_*B_SZ + b], acc_);                              \
    }                                                                          \
    A_ = acc_;                                                                 \
} while (0)

#define PASS2_J(J_, C_) do {                                                   \
    _Pragma("unroll")                                                          \
    for (int o = 0; o < DOUT; ++o) {                                           \
        const int jo_ = (J_)*DOUT + o;                                         \
        float uh_; UH_JO(jo_, uh_);                                            \
        atomicAdd(&slds[jo_*BSUB + (bb ^ (jo_ & 31))], (C_)*uh_);              \
    }                                                                          \
} while (0)

// have_v=0: iter-0 (uniform c; 1/10 folded into reduce's pre_scale)
// have_v=1: agreement vs vT (iter-1: vT0; iter-2: vT0+vT1 presummed — exact since
//           b_ij accumulates: softmax(uh.v0 + uh.v1) = softmax(uh.(v0+v1)))
__global__ __launch_bounds__(256, 2)
void caps_phase(const float* __restrict__ u, const float* __restrict__ W,
                const float* __restrict__ vT, float* __restrict__ s_part, int have_v)
{
    __shared__ __align__(16) float Wl[IPR*WROW];   // 40960 B: one round's W
    __shared__ float slds[JO*BSUB];                // 20480 B: s accumulator [jo][b]
    const int tid  = threadIdx.x;
    const int lane = tid & 63;
    const int wid  = tid >> 6;        // 0..3
    const int bb   = lane & 31;       // b within block
    const int ih   = lane >> 5;       // half-wave selects i within pair
    const int il   = wid*2 + ih;      // 0..7: i-slot within the staged round
    // bg in HIGH bits: the 8 blocks sharing a W chunk sit at bid stride 128 == 0 (mod 8)
    // -> same XCD -> chunk fetched into one L2.
    const int bg   = blockIdx.x >> 7; // 0..7
    const int ch   = blockIdx.x & 127;
    const int b    = bg*BSUB + bb;

#pragma unroll
    for (int k = 0; k < 5; ++k)                     // 5120 floats = 1280 float4
        ((float4*)slds)[k*256 + tid] = float4{0.f,0.f,0.f,0.f};

    for (int r = 0; r < 2; ++r) {
        __syncthreads();   // slds init visible (r=0) / prior-round Wl readers done (r=1)
        // ---- stage round's W: 8 i x 1280 floats = 40960 B contiguous, coalesced ----
        const float* wsrc = W + (size_t)(ch*IC + r*IPR)*WROW;
#pragma unroll
        for (int k = 0; k < 10; ++k)
            ((float4*)Wl)[k*256 + tid] = ((const float4*)wsrc)[k*256 + tid];
        __syncthreads();

        const int ig = ch*IC + r*IPR + il;                    // this lane's i
        const float* up = u + ((size_t)b*N_SZ + ig)*DIN;      // ih-halves share lines
        const float4 ua = ((const float4*)up)[0];
        const float4 ub = ((const float4*)up)[1];
        const float* wbase = Wl + il*WROW;                    // 2 addrs/wave -> free bcast

        // softmax coefficients as NAMED SCALARS (no arrays -> no scratch demotion)
        float c0=1.f,c1=1.f,c2=1.f,c3=1.f,c4=1.f,c5=1.f,c6=1.f,c7=1.f,c8=1.f,c9=1.f;
        if (have_v) {
            float A0,A1,A2,A3,A4,A5,A6,A7,A8,A9;
            PASS1_J(0,A0); PASS1_J(1,A1); PASS1_J(2,A2); PASS1_J(3,A3); PASS1_J(4,A4);
            PASS1_J(5,A5); PASS1_J(6,A6); PASS1_J(7,A7); PASS1_J(8,A8); PASS1_J(9,A9);
            float m = fmaxf(fmaxf(fmaxf(A0,A1), fmaxf(A2,A3)),
                            fmaxf(fmaxf(A4,A5), fmaxf(A6,A7)));
            m = fmaxf(m, fmaxf(A8,A9));
            const float e0=__expf(A0-m), e1=__expf(A1-m), e2=__expf(A2-m),
                        e3=__expf(A3-m), e4=__expf(A4-m), e5=__expf(A5-m),
                        e6=__expf(A6-m), e7=__expf(A7-m), e8=__expf(A8-m),
                        e9=__expf(A9-m);
            const float s = ((e0+e1)+(e2+e3)) + ((e4+e5)+(e6+e7)) + (e8+e9);
            const float inv = 1.f/s;
            c0=e0*inv; c1=e1*inv; c2=e2*inv; c3=e3*inv; c4=e4*inv;
            c5=e5*inv; c6=e6*inv; c7=e7*inv; c8=e8*inv; c9=e9*inv;
        }
        // ---- pass 2: s[jo][b] += c_j * uh[jo]  (recompute uh from LDS) ----
        // swizzled row: 32 lanes -> 32 banks; ih-halves hit the same cell by
        // design (different i contributions) — the DS atomic handles it.
        PASS2_J(0,c0); PASS2_J(1,c1); PASS2_J(2,c2); PASS2_J(3,c3); PASS2_J(4,c4);
        PASS2_J(5,c5); PASS2_J(6,c6); PASS2_J(7,c7); PASS2_J(8,c8); PASS2_J(9,c9);
    }
    __syncthreads();
    // ---- deposit partial [ch][jo][bg*32 .. +32], coalesced 128 B runs ----
    float* outp = s_part + (size_t)ch*(JO*B_SZ) + bg*BSUB;
    for (int k = tid; k < JO*BSUB; k += 256) {
        const int jo = k >> 5, b2 = k & 31;
        outp[jo*B_SZ + b2] = slds[jo*BSUB + (b2 ^ (jo & 31))];
    }
}

// Sum the 128 chunk partials; overwrite chunk-0 slice as s_sum[jo][b]. Coalesced.
__global__ __launch_bounds__(256)
void caps_reduceA(float* __restrict__ s_part, float pre_scale)
{
    const int idx = blockIdx.x*256 + threadIdx.x;      // < 40960
    float s = 0.f;
    for (int c = 0; c < NCH; ++c) s += s_part[(size_t)c*(JO*B_SZ) + idx];
    s_part[idx] = s * pre_scale;
}

// squash per (b,j); write vT_out = v (+ vT_prev), or final outputs.
__global__ __launch_bounds__(256)
void caps_squash(const float* __restrict__ s_sum, const float* __restrict__ vT_prev,
                 float* __restrict__ vT_out, float* __restrict__ out_v,
                 float* __restrict__ out_logit)
{
    const int t = blockIdx.x*256 + threadIdx.x;        // < 2560
    const int b = t / C_SZ, j = t % C_SZ;
    float sv[DOUT]; float n2 = 0.f;
#pragma unroll
    for (int o = 0; o < DOUT; ++o) {
        const float x = s_sum[(j*DOUT + o)*B_SZ + b];
        sv[o] = x; n2 = fmaf(x, x, n2);
    }
    const float norm  = sqrtf(n2);
    const float nc    = fmaxf(norm, 1e-7f);
    const float scale = 1.f - 1.f/(1.f + nc*nc);       // matches reference
    const float inv   = scale / nc;
    if (vT_out) {
#pragma unroll
        for (int o = 0; o < DOUT; ++o) {
            const float v = sv[o]*inv;
            const float p = vT_prev ? vT_prev[(j*DOUT + o)*B_SZ + b] : 0.f;
            vT_out[(j*DOUT + o)*B_SZ + b] = v + p;     // iter-1 writes v0+v1 directly
        }
    }
    if (out_v) {
        float q = 0.f;
#pragma unroll
        for (int o = 0; o < DOUT; ++o) {
            const float v = sv[o]*inv;
            out_v[(size_t)b*JO + j*DOUT + o] = v;      // [256,10,16]
            q = fmaf(v, v, q);
        }
        out_logit[t] = sqrtf(q);                       // [256,10]
    }
}

extern "C" void kernel_launch(void* const* d_in, const int* in_sizes, int n_in,
                              void* d_out, int out_size, void* d_ws, size_t ws_size,
                              hipStream_t stream)
{
    const float* u = (const float*)d_in[0];   // [256,2048,8]
    const float* W = (const float*)d_in[1];   // [2048,10,16,8]
    float* out_v     = (float*)d_out;         // [256,10,16]
    float* out_logit = out_v + B_SZ*JO;       // [256,10]

    float* s_part = (float*)d_ws;             // [128][160][256] f32; chunk0 doubles as s_sum
    float* vT0    = s_part + (size_t)NCH*JO*B_SZ;
    float* vsumT  = vT0 + JO*B_SZ;

    dim3 blk(256), gphase(NCH*NBG), gred(JO*B_SZ/256), gsq(B_SZ*C_SZ/256);

    // iter 0: uniform c (softmax of zeros = 1/10 -> pre_scale)
    caps_phase<<<gphase, blk, 0, stream>>>(u, W, nullptr, s_part, 0);
    caps_reduceA<<<gred, blk, 0, stream>>>(s_part, 0.1f);
    caps_squash<<<gsq, blk, 0, stream>>>(s_part, nullptr, vT0, nullptr, nullptr);
    // iter 1: b = uh.v0
    caps_phase<<<gphase, blk, 0, stream>>>(u, W, vT0, s_part, 1);
    caps_reduceA<<<gred, blk, 0, stream>>>(s_part, 1.0f);
    caps_squash<<<gsq, blk, 0, stream>>>(s_part, vT0, vsumT, nullptr, nullptr);
    // iter 2: b = uh.(v0+v1); final squash -> outputs
    caps_phase<<<gphase, blk, 0, stream>>>(u, W, vsumT, s_part, 1);
    caps_reduceA<<<gred, blk, 0, stream>>>(s_part, 1.0f);
    caps_squash<<<gsq, blk, 0, stream>>>(s_part, nullptr, nullptr, out_v, out_logit);
}

// Round 6
// 1052.098 us; speedup vs baseline: 1.8430x; 1.8430x over previous
//
#include <hip/hip_runtime.h>

// CapsNet dynamic routing, B=256 N=2048 C=10 D_IN=8 D_OUT=16, ROUTING_ITERS=3.
// R6 = R1's phase kernel (the ONLY body proven to allocate cleanly: VGPR 96,
// WRITE exactly 20 MB, no scratch phantom) with ONE swap: W rows staged into
// LDS per p-round (coalesced float4) instead of wave-uniform scalar-path
// global reads (R1's measured bottleneck: VALUBusy 15%, latency-bound);
// v moves from LDS to direct global reads (coalesced 256 B runs).
// R4/R5's restructured bodies produced ~330 MB/dispatch of phantom scratch
// traffic -- their structure is abandoned, not patched.
// LDS: Wl 40 KB + slds 40 KB = 80 KB -> 2 blocks/CU (8 waves/CU, same as R1).
// ws: s_part [128][160][256] f32 (20.97 MB) + vT0 + vsumT (160 KB each).

#define B_SZ  256
#define N_SZ  2048
#define C_SZ  10
#define DIN   8
#define DOUT  16
#define JO    (C_SZ*DOUT)   // 160
#define IC    16            // i's per chunk (per block)
#define NCH   (N_SZ/IC)     // 128 chunks
#define WROW  (JO*DIN)      // 1280 floats per i

__device__ __forceinline__ void softmax10(float* a) {
    float m = a[0];
#pragma unroll
    for (int j = 1; j < C_SZ; ++j) m = fmaxf(m, a[j]);
    float s = 0.f;
#pragma unroll
    for (int j = 0; j < C_SZ; ++j) { a[j] = __expf(a[j] - m); s += a[j]; }
    float inv = 1.f / s;
#pragma unroll
    for (int j = 0; j < C_SZ; ++j) a[j] *= inv;
}

// have_v=0: iter-0 (uniform c; 1/10 folded into reduce's pre_scale)
// have_v=1: agreement vs vT (iter-1: vT0; iter-2: vT0+vT1 presummed — exact since
//           b_ij accumulates: softmax(uh.v0 + uh.v1) = softmax(uh.(v0+v1)))
__global__ __launch_bounds__(256, 2)
void caps_phase(const float* __restrict__ u, const float* __restrict__ W,
                const float* __restrict__ vT, float* __restrict__ s_part, int have_v)
{
    __shared__ __align__(16) float Wl[8*WROW];   // 40960 B: the 8 i's active this p
    __shared__ float slds[JO*64];                // 40960 B: s accumulator [jo][64b]
    const int tid  = threadIdx.x;
    const int lane = tid & 63;
    const int wid  = tid >> 6;           // 0..3
    const int bg   = blockIdx.x & 3;     // which 64-b group (R1 mapping)
    const int ic   = blockIdx.x >> 2;    // which i-chunk
    const int b    = bg*64 + lane;

    for (int k = tid; k < JO*64; k += 256) slds[k] = 0.f;

    for (int p = 0; p < 2; ++p) {
        __syncthreads();   // slds init visible (p=0) / prior-round Wl readers done (p=1)
        // ---- stage the 8 active W rows: slot s <-> wave s>>1, pair s&1 ----
        // global i for slot s: ic*16 + (s>>1)*4 + p*2 + (s&1); 5 KB contiguous each.
#pragma unroll
        for (int slot = 0; slot < 8; ++slot) {
            const float* src = W + (size_t)(ic*IC + (slot>>1)*4 + p*2 + (slot&1))*WROW;
            float4* dst = (float4*)(Wl + slot*WROW);
            for (int k2 = tid; k2 < WROW/4; k2 += 256)     // 320 float4, coalesced
                dst[k2] = ((const float4*)src)[k2];
        }
        __syncthreads();

        // ---- R1 body: wave-uniform i pair, per-lane b ----
        const int i0 = ic*IC + wid*4 + p*2;
        const float* up = u + ((size_t)b*N_SZ + i0)*DIN;   // 64 B contiguous per lane
        float u0[8], u1[8];
        {
            float4 x0 = ((const float4*)up)[0];
            float4 x1 = ((const float4*)up)[1];
            float4 x2 = ((const float4*)up)[2];
            float4 x3 = ((const float4*)up)[3];
            u0[0]=x0.x; u0[1]=x0.y; u0[2]=x0.z; u0[3]=x0.w;
            u0[4]=x1.x; u0[5]=x1.y; u0[6]=x1.z; u0[7]=x1.w;
            u1[0]=x2.x; u1[1]=x2.y; u1[2]=x2.z; u1[3]=x2.w;
            u1[4]=x3.x; u1[5]=x3.y; u1[6]=x3.z; u1[7]=x3.w;
        }
        const float* W0 = Wl + (wid*2+0)*WROW;   // wave-uniform -> LDS broadcast reads
        const float* W1 = Wl + (wid*2+1)*WROW;

        float c0[C_SZ], c1[C_SZ];
        if (have_v) {
            // pass 1: agreement logits a[j] = sum_o uh[j,o] * v[j,o]
#pragma unroll
            for (int j = 0; j < C_SZ; ++j) {
                float acc0 = 0.f, acc1 = 0.f;
#pragma unroll
                for (int o = 0; o < DOUT; ++o) {
                    const int jo = j*DOUT + o;
                    const float4 a0 = ((const float4*)(W0 + jo*DIN))[0];
                    const float4 a1 = ((const float4*)(W0 + jo*DIN))[1];
                    const float4 b0 = ((const float4*)(W1 + jo*DIN))[0];
                    const float4 b1 = ((const float4*)(W1 + jo*DIN))[1];
                    float uh0 = a0.x*u0[0];
                    uh0 = fmaf(a0.y,u0[1],uh0); uh0 = fmaf(a0.z,u0[2],uh0); uh0 = fmaf(a0.w,u0[3],uh0);
                    uh0 = fmaf(a1.x,u0[4],uh0); uh0 = fmaf(a1.y,u0[5],uh0);
                    uh0 = fmaf(a1.z,u0[6],uh0); uh0 = fmaf(a1.w,u0[7],uh0);
                    float uh1 = b0.x*u1[0];
                    uh1 = fmaf(b0.y,u1[1],uh1); uh1 = fmaf(b0.z,u1[2],uh1); uh1 = fmaf(b0.w,u1[3],uh1);
                    uh1 = fmaf(b1.x,u1[4],uh1); uh1 = fmaf(b1.y,u1[5],uh1);
                    uh1 = fmaf(b1.z,u1[6],uh1); uh1 = fmaf(b1.w,u1[7],uh1);
                    const float vv = vT[jo*B_SZ + b];       // coalesced 256 B run
                    acc0 = fmaf(uh0, vv, acc0);
                    acc1 = fmaf(uh1, vv, acc1);
                }
                c0[j] = acc0; c1[j] = acc1;
            }
            softmax10(c0);   // per-lane, no divergence (R1-proven construct)
            softmax10(c1);
        }
        // pass 2: s[jo][b] += c0[j]*uh0 + c1[j]*uh1 (recompute uh from LDS)
#pragma unroll
        for (int j = 0; j < C_SZ; ++j) {
            const float w0c = have_v ? c0[j] : 1.f;
            const float w1c = have_v ? c1[j] : 1.f;
#pragma unroll
            for (int o = 0; o < DOUT; ++o) {
                const int jo = j*DOUT + o;
                const float4 a0 = ((const float4*)(W0 + jo*DIN))[0];
                const float4 a1 = ((const float4*)(W0 + jo*DIN))[1];
                const float4 b0 = ((const float4*)(W1 + jo*DIN))[0];
                const float4 b1 = ((const float4*)(W1 + jo*DIN))[1];
                float uh0 = a0.x*u0[0];
                uh0 = fmaf(a0.y,u0[1],uh0); uh0 = fmaf(a0.z,u0[2],uh0); uh0 = fmaf(a0.w,u0[3],uh0);
                uh0 = fmaf(a1.x,u0[4],uh0); uh0 = fmaf(a1.y,u0[5],uh0);
                uh0 = fmaf(a1.z,u0[6],uh0); uh0 = fmaf(a1.w,u0[7],uh0);
                float uh1 = b0.x*u1[0];
                uh1 = fmaf(b0.y,u1[1],uh1); uh1 = fmaf(b0.z,u1[2],uh1); uh1 = fmaf(b0.w,u1[3],uh1);
                uh1 = fmaf(b1.x,u1[4],uh1); uh1 = fmaf(b1.y,u1[5],uh1);
                uh1 = fmaf(b1.z,u1[6],uh1); uh1 = fmaf(b1.w,u1[7],uh1);
                const float val = fmaf(w0c, uh0, w1c*uh1);
                // 64 lanes -> 32 banks 2-row, conflict-free (2-way is free per m136)
                atomicAdd(&slds[jo*64 + (lane ^ (jo & 31))], val);
            }
        }
    }
    __syncthreads();
    // ---- deposit partial [ch][jo][bg*64 .. +64], coalesced 256 B runs ----
    float* outp = s_part + (size_t)ic*(JO*B_SZ) + bg*64;
    for (int k = tid; k < JO*64; k += 256) {
        const int jo = k >> 6, b2 = k & 63;
        outp[jo*B_SZ + b2] = slds[jo*64 + (b2 ^ (jo & 31))];
    }
}

// Sum the 128 chunk partials; overwrite chunk-0 slice as s_sum[jo][b]. Coalesced.
__global__ __launch_bounds__(256)
void caps_reduceA(float* __restrict__ s_part, float pre_scale)
{
    const int idx = blockIdx.x*256 + threadIdx.x;      // < 40960
    float s = 0.f;
    for (int c = 0; c < NCH; ++c) s += s_part[(size_t)c*(JO*B_SZ) + idx];
    s_part[idx] = s * pre_scale;
}

// squash per (b,j); write vT_out = v (+ vT_prev), or final outputs.
__global__ __launch_bounds__(256)
void caps_squash(const float* __restrict__ s_sum, const float* __restrict__ vT_prev,
                 float* __restrict__ vT_out, float* __restrict__ out_v,
                 float* __restrict__ out_logit)
{
    const int t = blockIdx.x*256 + threadIdx.x;        // < 2560
    const int b = t / C_SZ, j = t % C_SZ;
    float sv[DOUT]; float n2 = 0.f;
#pragma unroll
    for (int o = 0; o < DOUT; ++o) {
        const float x = s_sum[(j*DOUT + o)*B_SZ + b];
        sv[o] = x; n2 = fmaf(x, x, n2);
    }
    const float norm  = sqrtf(n2);
    const float nc    = fmaxf(norm, 1e-7f);
    const float scale = 1.f - 1.f/(1.f + nc*nc);       // matches reference
    const float inv   = scale / nc;
    if (vT_out) {
#pragma unroll
        for (int o = 0; o < DOUT; ++o) {
            const float v = sv[o]*inv;
            const float p = vT_prev ? vT_prev[(j*DOUT + o)*B_SZ + b] : 0.f;
            vT_out[(j*DOUT + o)*B_SZ + b] = v + p;     // iter-1 writes v0+v1 directly
        }
    }
    if (out_v) {
        float q = 0.f;
#pragma unroll
        for (int o = 0; o < DOUT; ++o) {
            const float v = sv[o]*inv;
            out_v[(size_t)b*JO + j*DOUT + o] = v;      // [256,10,16]
            q = fmaf(v, v, q);
        }
        out_logit[t] = sqrtf(q);                       // [256,10]
    }
}

extern "C" void kernel_launch(void* const* d_in, const int* in_sizes, int n_in,
                              void* d_out, int out_size, void* d_ws, size_t ws_size,
                              hipStream_t stream)
{
    const float* u = (const float*)d_in[0];   // [256,2048,8]
    const float* W = (const float*)d_in[1];   // [2048,10,16,8]
    float* out_v     = (float*)d_out;         // [256,10,16]
    float* out_logit = out_v + B_SZ*JO;       // [256,10]

    float* s_part = (float*)d_ws;             // [128][160][256] f32; chunk0 doubles as s_sum
    float* vT0    = s_part + (size_t)NCH*JO*B_SZ;
    float* vsumT  = vT0 + JO*B_SZ;

    dim3 blk(256), gphase(NCH*4), gred(JO*B_SZ/256), gsq(B_SZ*C_SZ/256);

    // iter 0: uniform c (softmax of zeros = 1/10 -> pre_scale)
    caps_phase<<<gphase, blk, 0, stream>>>(u, W, nullptr, s_part, 0);
    caps_reduceA<<<gred, blk, 0, stream>>>(s_part, 0.1f);
    caps_squash<<<gsq, blk, 0, stream>>>(s_part, nullptr, vT0, nullptr, nullptr);
    // iter 1: b = uh.v0
    caps_phase<<<gphase, blk, 0, stream>>>(u, W, vT0, s_part, 1);
    caps_reduceA<<<gred, blk, 0, stream>>>(s_part, 1.0f);
    caps_squash<<<gsq, blk, 0, stream>>>(s_part, vT0, vsumT, nullptr, nullptr);
    // iter 2: b = uh.(v0+v1); final squash -> outputs
    caps_phase<<<gphase, blk, 0, stream>>>(u, W, vsumT, s_part, 1);
    caps_reduceA<<<gred, blk, 0, stream>>>(s_part, 1.0f);
    caps_squash<<<gsq, blk, 0, stream>>>(s_part, nullptr, nullptr, out_v, out_logit);
}

// Round 7
// 301.394 us; speedup vs baseline: 6.4336x; 3.4908x over previous
//
#include <hip/hip_runtime.h>
#include <hip/hip_fp16.h>

// CapsNet dynamic routing, B=256 N=2048 C=10 D_IN=8 D_OUT=16, ROUTING_ITERS=3.
// R7: STOP recomputing u_hat (3 rounds of phantom-scratch codegen failures in
// dense recompute bodies). Materialize u_hat ONCE in fp16 [i][jo][b] (160 MB,
// L3-resident); all consumers are small-body streaming kernels (VGPR<48):
//   build_uhat : u x W -> uhat fp16            (once,  ~35 us)
//   caps_c     : agreement+softmax -> c        (x2,    ~30 us)  [R1-proven a[10] construct]
//   caps_s     : s_part[ch][jo][b] = sum_i c*uh (x3,   ~30 us)  [no atomics, scalar acc]
//   reduceA/squash : unchanged, byte-exact proven.
// ws: uhat 160 MB + s_part 21 MB + cbuf 21 MB + vT0/vsumT ~= 210 MB.

#define B_SZ  256
#define N_SZ  2048
#define C_SZ  10
#define DIN   8
#define DOUT  16
#define JO    (C_SZ*DOUT)   // 160
#define IC    16            // i's per chunk in caps_s
#define NCH   (N_SZ/IC)     // 128
#define WROW  (JO*DIN)      // 1280 floats per i

__device__ __forceinline__ void softmax10(float* a) {
    float m = a[0];
#pragma unroll
    for (int j = 1; j < C_SZ; ++j) m = fmaxf(m, a[j]);
    float s = 0.f;
#pragma unroll
    for (int j = 0; j < C_SZ; ++j) { a[j] = __expf(a[j] - m); s += a[j]; }
    float inv = 1.f / s;
#pragma unroll
    for (int j = 0; j < C_SZ; ++j) a[j] *= inv;
}

// uhat[i][jo][b] = dot(W[i][jo][:], u[b][i][:])  (fp32 math, fp16 store)
__global__ __launch_bounds__(256)
void build_uhat(const float* __restrict__ u, const float* __restrict__ W,
                __half* __restrict__ uhat)
{
    __shared__ __align__(16) float Wl[WROW];       // 5 KB: W[i]
    const int i = blockIdx.x;
    const int b = threadIdx.x;
    for (int k = b; k < WROW/4; k += 256)          // 320 float4, coalesced
        ((float4*)Wl)[k] = ((const float4*)(W + (size_t)i*WROW))[k];
    __syncthreads();
    const float* up = u + ((size_t)b*N_SZ + i)*DIN;   // 32 B/lane, 2x overfetch ok
    const float4 ua = ((const float4*)up)[0];
    const float4 ub = ((const float4*)up)[1];
    __half* dst = uhat + (size_t)i*JO*B_SZ + b;
#pragma unroll 2
    for (int jo = 0; jo < JO; ++jo) {
        const float4 w0 = ((const float4*)(Wl + jo*DIN))[0];   // block-uniform addr
        const float4 w1 = ((const float4*)(Wl + jo*DIN))[1];   //  -> LDS broadcast
        float uh = w0.x*ua.x;
        uh = fmaf(w0.y, ua.y, uh); uh = fmaf(w0.z, ua.z, uh); uh = fmaf(w0.w, ua.w, uh);
        uh = fmaf(w1.x, ub.x, uh); uh = fmaf(w1.y, ub.y, uh);
        uh = fmaf(w1.z, ub.z, uh); uh = fmaf(w1.w, ub.w, uh);
        dst[(size_t)jo*B_SZ] = __float2half(uh);   // 512 B/wave contiguous
    }
}

// c[i][j][b] = softmax_j( sum_o uhat[i][jo][b] * vT[jo][b] )
__global__ __launch_bounds__(256)
void caps_c(const __half* __restrict__ uhat, const float* __restrict__ vT,
            float* __restrict__ cbuf)
{
    const int i = blockIdx.x;
    const int b = threadIdx.x;
    const __half* up = uhat + (size_t)i*JO*B_SZ + b;
    float a[C_SZ];                                  // static-indexed (R1-proven)
#pragma unroll
    for (int j = 0; j < C_SZ; ++j) {
        float acc = 0.f;
#pragma unroll
        for (int o = 0; o < DOUT; ++o) {
            const int jo = j*DOUT + o;
            acc = fmaf(__half2float(up[(size_t)jo*B_SZ]), vT[jo*B_SZ + b], acc);
        }
        a[j] = acc;
    }
    softmax10(a);
#pragma unroll
    for (int j = 0; j < C_SZ; ++j)
        cbuf[((size_t)i*C_SZ + j)*B_SZ + b] = a[j];  // 1 KB runs, coalesced
}

// s_part[ch][jo][b] = sum_{i in chunk} c[i][j][b] * uhat[i][jo][b]
// have_c=0: c = 0.1 (iter-0 uniform softmax)
__global__ __launch_bounds__(256)
void caps_s(const __half* __restrict__ uhat, const float* __restrict__ cbuf,
            float* __restrict__ s_part, int have_c)
{
    __shared__ float cl[IC*C_SZ*64];                // 40 KB: [il][j][bl]
    const int ch = blockIdx.x >> 2;
    const int bg = blockIdx.x & 3;
    const int t  = threadIdx.x;
    const int bl = t & 63;
    const int b  = bg*64 + bl;
    const int jo0 = (t >> 6)*40;                    // wave-uniform jo range
    if (have_c) {
        for (int k = t; k < IC*C_SZ*64; k += 256) { // coalesced 256 B runs
            const int il = k / (C_SZ*64);
            const int rem = k - il*(C_SZ*64);
            cl[k] = cbuf[((size_t)(ch*IC + il)*C_SZ + (rem >> 6))*B_SZ + bg*64 + (rem & 63)];
        }
    } else {
        for (int k = t; k < IC*C_SZ*64; k += 256) cl[k] = 0.1f;
    }
    __syncthreads();
    for (int k = 0; k < 40; ++k) {
        const int jo = jo0 + k;                     // wave-uniform
        const float* cp = cl + ((jo >> 4) << 6) + bl;   // stride-1 over lanes: conflict-free
        const __half* up = uhat + ((size_t)(ch*IC)*JO + jo)*B_SZ + b;
        float acc0 = 0.f, acc1 = 0.f;
#pragma unroll
        for (int il = 0; il < IC; il += 2) {        // 2 chains, scalar accumulators
            acc0 = fmaf(cp[(il  )*(C_SZ*64)], __half2float(up[(size_t)(il  )*JO*B_SZ]), acc0);
            acc1 = fmaf(cp[(il+1)*(C_SZ*64)], __half2float(up[(size_t)(il+1)*JO*B_SZ]), acc1);
        }
        s_part[((size_t)ch*JO + jo)*B_SZ + b] = acc0 + acc1;   // coalesced
    }
}

// Sum the 128 chunk partials; overwrite chunk-0 slice as s_sum[jo][b].
__global__ __launch_bounds__(256)
void caps_reduceA(float* __restrict__ s_part, float pre_scale)
{
    const int idx = blockIdx.x*256 + threadIdx.x;      // < 40960
    float s = 0.f;
    for (int c = 0; c < NCH; ++c) s += s_part[(size_t)c*(JO*B_SZ) + idx];
    s_part[idx] = s * pre_scale;
}

// squash per (b,j); write vT_out = v (+ vT_prev), or final outputs.
__global__ __launch_bounds__(256)
void caps_squash(const float* __restrict__ s_sum, const float* __restrict__ vT_prev,
                 float* __restrict__ vT_out, float* __restrict__ out_v,
                 float* __restrict__ out_logit)
{
    const int t = blockIdx.x*256 + threadIdx.x;        // < 2560
    const int b = t / C_SZ, j = t % C_SZ;
    float sv[DOUT]; float n2 = 0.f;
#pragma unroll
    for (int o = 0; o < DOUT; ++o) {
        const float x = s_sum[(j*DOUT + o)*B_SZ + b];
        sv[o] = x; n2 = fmaf(x, x, n2);
    }
    const float norm  = sqrtf(n2);
    const float nc    = fmaxf(norm, 1e-7f);
    const float scale = 1.f - 1.f/(1.f + nc*nc);       // matches reference
    const float inv   = scale / nc;
    if (vT_out) {
#pragma unroll
        for (int o = 0; o < DOUT; ++o) {
            const float v = sv[o]*inv;
            const float p = vT_prev ? vT_prev[(j*DOUT + o)*B_SZ + b] : 0.f;
            vT_out[(j*DOUT + o)*B_SZ + b] = v + p;     // iter-1 writes v0+v1 directly
        }
    }
    if (out_v) {
        float q = 0.f;
#pragma unroll
        for (int o = 0; o < DOUT; ++o) {
            const float v = sv[o]*inv;
            out_v[(size_t)b*JO + j*DOUT + o] = v;      // [256,10,16]
            q = fmaf(v, v, q);
        }
        out_logit[t] = sqrtf(q);                       // [256,10]
    }
}

extern "C" void kernel_launch(void* const* d_in, const int* in_sizes, int n_in,
                              void* d_out, int out_size, void* d_ws, size_t ws_size,
                              hipStream_t stream)
{
    const float* u = (const float*)d_in[0];   // [256,2048,8]
    const float* W = (const float*)d_in[1];   // [2048,10,16,8]
    float* out_v     = (float*)d_out;         // [256,10,16]
    float* out_logit = out_v + B_SZ*JO;       // [256,10]

    __half* uhat  = (__half*)d_ws;                                    // 167,772,160 B
    float* s_part = (float*)((char*)d_ws + (size_t)N_SZ*JO*B_SZ*2);   // 20,971,520 B
    float* cbuf   = s_part + (size_t)NCH*JO*B_SZ;                     // 20,971,520 B
    float* vT0    = cbuf + (size_t)N_SZ*C_SZ*B_SZ;                    // 163,840 B
    float* vsumT  = vT0 + JO*B_SZ;                                    // 163,840 B

    dim3 blk(256), gbuild(N_SZ), gc(N_SZ), gs(NCH*4), gred(JO*B_SZ/256), gsq(B_SZ*C_SZ/256);

    build_uhat<<<gbuild, blk, 0, stream>>>(u, W, uhat);
    // iter 0: c uniform 0.1 (folded into caps_s)
    caps_s<<<gs, blk, 0, stream>>>(uhat, nullptr, s_part, 0);
    caps_reduceA<<<gred, blk, 0, stream>>>(s_part, 1.0f);
    caps_squash<<<gsq, blk, 0, stream>>>(s_part, nullptr, vT0, nullptr, nullptr);
    // iter 1: c = softmax(uh.v0)
    caps_c<<<gc, blk, 0, stream>>>(uhat, vT0, cbuf);
    caps_s<<<gs, blk, 0, stream>>>(uhat, cbuf, s_part, 1);
    caps_reduceA<<<gred, blk, 0, stream>>>(s_part, 1.0f);
    caps_squash<<<gsq, blk, 0, stream>>>(s_part, vT0, vsumT, nullptr, nullptr);
    // iter 2: c = softmax(uh.(v0+v1)); final squash -> outputs
    caps_c<<<gc, blk, 0, stream>>>(uhat, vsumT, cbuf);
    caps_s<<<gs, blk, 0, stream>>>(uhat, cbuf, s_part, 1);
    caps_reduceA<<<gred, blk, 0, stream>>>(s_part, 1.0f);
    caps_squash<<<gsq, blk, 0, stream>>>(s_part, nullptr, nullptr, out_v, out_logit);
}